// Round 3
// baseline (137.606 us; speedup 1.0000x reference)
//
#include <hip/hip_runtime.h>

#define NQ   6
#define DIM  64
#define OH   63
#define HH   128
#define CIN  4
#define NB   128
#define PSTR 80   // P row stride in shorts (160B = 16B-aligned)

typedef __attribute__((ext_vector_type(8))) short short8;
typedef __attribute__((ext_vector_type(4))) float f32x4;

__device__ __forceinline__ unsigned bf16_rne_u(float f) {
    unsigned u = __builtin_bit_cast(unsigned, f);
    return (u + 0x7fffu + ((u >> 16) & 1u)) >> 16;   // round-nearest-even
}

#if __has_builtin(__builtin_amdgcn_cvt_pk_bf16_f32)
__device__ __forceinline__ unsigned pk_bf16(float a, float b) {
    typedef __attribute__((ext_vector_type(2))) __bf16 bf16x2_t;
    bf16x2_t v = __builtin_amdgcn_cvt_pk_bf16_f32(a, b);
    return __builtin_bit_cast(unsigned, v);
}
#else
__device__ __forceinline__ unsigned pk_bf16(float a, float b) {
    return bf16_rne_u(a) | (bf16_rne_u(b) << 16);
}
#endif

// ---------------------------------------------------------------------------
// Fused prep: build the 64x64 circuit unitary in LDS (16 waves x 4 columns,
// rotation matrices computed once), then pack W = [Re U; Im U] into per-lane
// MFMA A-fragments split hi/lo bf16, written to d_ws.
//   wfrag layout: frag f (0..15 hi, 16..31 lo): mt=(f&15)>>1, t=f&1;
//   lane l holds A[m = mt*16 + (l&15)][k = t*32 + (l>>4)*8 + j], j=0..7.
// ---------------------------------------------------------------------------
__global__ __launch_bounds__(1024) void prep(const float* __restrict__ wts,
                                             short* __restrict__ wfrag) {
    __shared__ float2 rotm[12][4];          // {U00,U01,U10,U11} per (l,w)
    __shared__ float2 sUt[DIM * DIM];       // sUt[k*64 + i] = U[i][k]

    const int tid = threadIdx.x;

    if (tid < 12) {
        const float phi = wts[tid * 3 + 0];
        const float th  = wts[tid * 3 + 1];
        const float om  = wts[tid * 3 + 2];
        const float hc = cosf(0.5f * th);
        const float hs = sinf(0.5f * th);
        const float ap = -0.5f * (phi + om);
        const float am = -0.5f * (phi - om);
        const float2 ep = make_float2(cosf(ap), sinf(ap));
        const float2 em = make_float2(cosf(am), sinf(am));
        rotm[tid][0] = make_float2( ep.x * hc,  ep.y * hc);   // U00
        rotm[tid][1] = make_float2(-em.x * hs,  em.y * hs);   // U01
        rotm[tid][2] = make_float2( em.x * hs,  em.y * hs);   // U10
        rotm[tid][3] = make_float2( ep.x * hc, -ep.y * hc);   // U11
    }
    __syncthreads();

    const int lane = tid & 63;
    const int wv   = tid >> 6;              // 0..15

#pragma unroll
    for (int cc = 0; cc < 4; ++cc) {
        const int col = wv * 4 + cc;
        float2 amp = make_float2(lane == col ? 1.0f : 0.0f, 0.0f);
#pragma unroll
        for (int rep = 0; rep < 2; ++rep) {
#pragma unroll
            for (int l = 0; l < 2; ++l) {
#pragma unroll
                for (int w = 0; w < NQ; ++w) {
                    const float2 U00 = rotm[l * 6 + w][0];
                    const float2 U01 = rotm[l * 6 + w][1];
                    const float2 U10 = rotm[l * 6 + w][2];
                    const float2 U11 = rotm[l * 6 + w][3];
                    const int p = 5 - w;
                    const int bbit = (lane >> p) & 1;
                    const float px = __shfl_xor(amp.x, 1 << p, 64);
                    const float py = __shfl_xor(amp.y, 1 << p, 64);
                    const float2 ua = bbit ? U11 : U00;
                    const float2 ub = bbit ? U10 : U01;
                    float2 na;
                    na.x = ua.x * amp.x - ua.y * amp.y + ub.x * px - ub.y * py;
                    na.y = ua.x * amp.y + ua.y * amp.x + ub.x * py + ub.y * px;
                    amp = na;
                }
                const int r = (l == 0) ? 1 : 2;   // l % (NQ-1) + 1
#pragma unroll
                for (int w = 0; w < NQ; ++w) {
                    const int pc = 5 - w;
                    const int pt = 5 - ((w + r) % NQ);
                    const int src = lane ^ (((lane >> pc) & 1) << pt);
                    const float nx = __shfl(amp.x, src, 64);
                    const float ny = __shfl(amp.y, src, 64);
                    amp = make_float2(nx, ny);
                }
            }
        }
        sUt[col * DIM + lane] = amp;
    }
    __syncthreads();

    // phase 2: pack fragments (thread -> hi frag f = tid>>6 and lo frag f+16)
    {
        const int f  = tid >> 6;            // 0..15
        const int l  = lane;
        const int mt = f >> 1;
        const int t  = f & 1;
        const int m  = mt * 16 + (l & 15);
        short8 vhi, vlo;
#pragma unroll
        for (int j = 0; j < 8; ++j) {
            const int k = t * 32 + (l >> 4) * 8 + j;
            const float2 u = sUt[k * DIM + (m & 63)];
            const float val = (m < 64) ? u.x : u.y;
            const unsigned h = bf16_rne_u(val);
            vhi[j] = (short)h;
            const float fh = __builtin_bit_cast(float, h << 16);
            vlo[j] = (short)bf16_rne_u(val - fh);
        }
        ((int4*)wfrag)[f * 64 + l]        = __builtin_bit_cast(int4, vhi);
        ((int4*)wfrag)[(16 + f) * 64 + l] = __builtin_bit_cast(int4, vlo);
    }
}

// ---------------------------------------------------------------------------
// Main: 1 wave per (b,oy) row; 4 chunks of 16 samples (ox = ch*16 + n).
//  B-fragments of F built directly from global (no LDS): lane (qq,n) needs
//  F[k=qq*8+j][n] -> x[b, c, 2oy+kh, 2ox+kw] with c=qq>>1 (+2 for b1),
//  kh=(qq&1)*2+(j>>2), kw=j&3  == two float2 per row, 4 rows.
//  G = (Whi+Wlo)·F (32 MFMA), P = Gre^2+Gim^2 -> LDS -> Z = S·P (2 MFMA),
//  z_q = Z[q][n] / Z[6][n].
// ---------------------------------------------------------------------------
__global__ __launch_bounds__(256, 2) void qconv_mfma(const float* __restrict__ x,
                                                     const short* __restrict__ wfrag,
                                                     float* __restrict__ out) {
    __shared__ __align__(16) short sP[4][16 * PSTR];   // 10 KiB

    const int tid  = threadIdx.x;
    const int lane = tid & 63;
    const int wv   = tid >> 6;
    const int n    = lane & 15;
    const int qq   = lane >> 4;

    const int row = blockIdx.x * 4 + wv;   // 0..8063
    const int b   = row / OH;
    const int oy  = row - b * OH;

    // ---- W fragments (32 coalesced int4 loads, L2-resident) ----
    short8 whi[8][2], wlo[8][2];
    {
        const int4* wp = (const int4*)wfrag;
#pragma unroll
        for (int mt = 0; mt < 8; ++mt)
#pragma unroll
            for (int t = 0; t < 2; ++t) {
                const int f = mt * 2 + t;
                whi[mt][t] = __builtin_bit_cast(short8, wp[f * 64 + lane]);
                wlo[mt][t] = __builtin_bit_cast(short8, wp[(16 + f) * 64 + lane]);
            }
    }

    // ---- S fragments (rows 0..5 = Pauli-Z signs, row 6 = ones, rest 0) ----
    short8 sfr[2];
#pragma unroll
    for (int t = 0; t < 2; ++t) {
        short8 v;
#pragma unroll
        for (int j = 0; j < 8; ++j) {
            const int i = t * 32 + qq * 8 + j;
            unsigned short s;
            if (n < 6)       s = ((i >> (5 - n)) & 1) ? 0xBF80 : 0x3F80;
            else if (n == 6) s = 0x3F80;
            else             s = 0;
            v[j] = (short)s;
        }
        sfr[t] = v;
    }

    // ---- x row pointers for this lane's 4 (c,kh) rows ----
    const int c0  = qq >> 1;
    const int kh0 = (qq & 1) * 2;
    const float* xb  = x + (size_t)b * CIN * HH * HH;
    const float* r00 = xb + ((c0    ) * HH + 2 * oy + kh0    ) * HH;
    const float* r01 = xb + ((c0    ) * HH + 2 * oy + kh0 + 1) * HH;
    const float* r10 = xb + ((c0 + 2) * HH + 2 * oy + kh0    ) * HH;
    const float* r11 = xb + ((c0 + 2) * HH + 2 * oy + kh0 + 1) * HH;

    short* myP = sP[wv];

#pragma unroll
    for (int ch = 0; ch < 4; ++ch) {
        const int ox  = ch * 16 + n;
        const int oxl = min(ox, OH - 1);     // only clamps (ch=3, n=15)
        const int fo  = 2 * oxl;

        const float2 a0 = *(const float2*)(r00 + fo);
        const float2 a1 = *(const float2*)(r00 + fo + 2);
        const float2 b0 = *(const float2*)(r01 + fo);
        const float2 b1 = *(const float2*)(r01 + fo + 2);
        const float2 e0 = *(const float2*)(r10 + fo);
        const float2 e1 = *(const float2*)(r10 + fo + 2);
        const float2 d0 = *(const float2*)(r11 + fo);
        const float2 d1 = *(const float2*)(r11 + fo + 2);

        uint4 u0, u1;
        u0.x = pk_bf16(a0.x, a0.y);  u0.y = pk_bf16(a1.x, a1.y);
        u0.z = pk_bf16(b0.x, b0.y);  u0.w = pk_bf16(b1.x, b1.y);
        u1.x = pk_bf16(e0.x, e0.y);  u1.y = pk_bf16(e1.x, e1.y);
        u1.z = pk_bf16(d0.x, d0.y);  u1.w = pk_bf16(d1.x, d1.y);
        const short8 bf0 = __builtin_bit_cast(short8, u0);
        const short8 bf1 = __builtin_bit_cast(short8, u1);

        // ---- G = (Whi + Wlo) · F ----
        f32x4 acc[8];
#pragma unroll
        for (int mt = 0; mt < 8; ++mt) acc[mt] = (f32x4){0.f, 0.f, 0.f, 0.f};
#pragma unroll
        for (int mt = 0; mt < 8; ++mt) {
            acc[mt] = __builtin_amdgcn_mfma_f32_16x16x32_bf16(whi[mt][0], bf0, acc[mt], 0, 0, 0);
            acc[mt] = __builtin_amdgcn_mfma_f32_16x16x32_bf16(whi[mt][1], bf1, acc[mt], 0, 0, 0);
            acc[mt] = __builtin_amdgcn_mfma_f32_16x16x32_bf16(wlo[mt][0], bf0, acc[mt], 0, 0, 0);
            acc[mt] = __builtin_amdgcn_mfma_f32_16x16x32_bf16(wlo[mt][1], bf1, acc[mt], 0, 0, 0);
        }

        // ---- P = Gre^2 + Gim^2 -> bf16 (RNE) -> LDS ----
#pragma unroll
        for (int mt = 0; mt < 4; ++mt) {
            const float p0 = acc[mt][0] * acc[mt][0] + acc[mt + 4][0] * acc[mt + 4][0];
            const float p1 = acc[mt][1] * acc[mt][1] + acc[mt + 4][1] * acc[mt + 4][1];
            const float p2 = acc[mt][2] * acc[mt][2] + acc[mt + 4][2] * acc[mt + 4][2];
            const float p3 = acc[mt][3] * acc[mt][3] + acc[mt + 4][3] * acc[mt + 4][3];
            const unsigned w0 = pk_bf16(p0, p1);
            const unsigned w1 = pk_bf16(p2, p3);
            *((uint2*)(((unsigned*)myP) + n * (PSTR / 2) + mt * 8 + qq * 2)) =
                make_uint2(w0, w1);
        }

        // ---- Z = S · P ----
        const short8 p0f = *(const short8*)(myP + n * PSTR + qq * 8);
        const short8 p1f = *(const short8*)(myP + n * PSTR + 32 + qq * 8);
        f32x4 c2 = (f32x4){0.f, 0.f, 0.f, 0.f};
        c2 = __builtin_amdgcn_mfma_f32_16x16x32_bf16(sfr[0], p0f, c2, 0, 0, 0);
        c2 = __builtin_amdgcn_mfma_f32_16x16x32_bf16(sfr[1], p1f, c2, 0, 0, 0);

        // ---- normalize + store: Z row q = qq*4 + reg; norm = row 6 ----
        const float norm = __shfl(c2[2], 16 + n, 64);
        const float inv  = 1.0f / norm;
        if (ox < OH) {
            float* ob = out + ((size_t)b * NQ * OH + oy) * OH + ox;
            if (qq == 0) {
#pragma unroll
                for (int r = 0; r < 4; ++r) ob[(size_t)r * (OH * OH)] = c2[r] * inv;
            } else if (qq == 1) {
                ob[(size_t)4 * (OH * OH)] = c2[0] * inv;
                ob[(size_t)5 * (OH * OH)] = c2[1] * inv;
            }
        }
    }
}

extern "C" void kernel_launch(void* const* d_in, const int* in_sizes, int n_in,
                              void* d_out, int out_size, void* d_ws, size_t ws_size,
                              hipStream_t stream) {
    const float* x   = (const float*)d_in[0];   // (128, 4, 128, 128) f32
    const float* wts = (const float*)d_in[1];   // (2, 6, 3) f32
    float* out = (float*)d_out;                 // (128, 6, 63, 63) f32
    short* wfrag = (short*)d_ws;                // 32 KiB

    prep<<<1, 1024, 0, stream>>>(wts, wfrag);
    qconv_mfma<<<(NB * OH) / 4, 256, 0, stream>>>(x, wfrag, out);
}

// Round 4
// 132.107 us; speedup vs baseline: 1.0416x; 1.0416x over previous
//
#include <hip/hip_runtime.h>

#define NQ   6
#define DIM  64
#define OH   63
#define HH   128
#define CIN  4
#define NB   128
#define PSTR 80   // P row stride in shorts (160B = 16B-aligned)

typedef __attribute__((ext_vector_type(8))) short short8;
typedef __attribute__((ext_vector_type(4))) float f32x4;

__device__ __forceinline__ unsigned bf16_rne_u(float f) {
    unsigned u = __builtin_bit_cast(unsigned, f);
    return (u + 0x7fffu + ((u >> 16) & 1u)) >> 16;   // round-nearest-even
}

#if __has_builtin(__builtin_amdgcn_cvt_pk_bf16_f32)
__device__ __forceinline__ unsigned pk_bf16(float a, float b) {
    typedef __attribute__((ext_vector_type(2))) __bf16 bf16x2_t;
    bf16x2_t v = __builtin_amdgcn_cvt_pk_bf16_f32(a, b);
    return __builtin_bit_cast(unsigned, v);
}
#else
__device__ __forceinline__ unsigned pk_bf16(float a, float b) {
    return bf16_rne_u(a) | (bf16_rne_u(b) << 16);
}
#endif

// ---------------------------------------------------------------------------
// Fused prep: build the 64x64 circuit unitary in LDS (16 waves x 4 columns),
// then pack W = [Re U; Im U] into per-lane MFMA A-fragments split hi/lo bf16.
//   wfrag layout: frag f (0..15 hi, 16..31 lo): mt=(f&15)>>1, t=f&1;
//   lane l holds A[m = mt*16 + (l&15)][k = t*32 + (l>>4)*8 + j], j=0..7.
// ---------------------------------------------------------------------------
__global__ __launch_bounds__(1024) void prep(const float* __restrict__ wts,
                                             short* __restrict__ wfrag) {
    __shared__ float2 rotm[12][4];          // {U00,U01,U10,U11} per (l,w)
    __shared__ float2 sUt[DIM * DIM];       // sUt[k*64 + i] = U[i][k]

    const int tid = threadIdx.x;

    if (tid < 12) {
        const float phi = wts[tid * 3 + 0];
        const float th  = wts[tid * 3 + 1];
        const float om  = wts[tid * 3 + 2];
        const float hc = cosf(0.5f * th);
        const float hs = sinf(0.5f * th);
        const float ap = -0.5f * (phi + om);
        const float am = -0.5f * (phi - om);
        const float2 ep = make_float2(cosf(ap), sinf(ap));
        const float2 em = make_float2(cosf(am), sinf(am));
        rotm[tid][0] = make_float2( ep.x * hc,  ep.y * hc);   // U00
        rotm[tid][1] = make_float2(-em.x * hs,  em.y * hs);   // U01
        rotm[tid][2] = make_float2( em.x * hs,  em.y * hs);   // U10
        rotm[tid][3] = make_float2( ep.x * hc, -ep.y * hc);   // U11
    }
    __syncthreads();

    const int lane = tid & 63;
    const int wv   = tid >> 6;              // 0..15

#pragma unroll
    for (int cc = 0; cc < 4; ++cc) {
        const int col = wv * 4 + cc;
        float2 amp = make_float2(lane == col ? 1.0f : 0.0f, 0.0f);
#pragma unroll
        for (int rep = 0; rep < 2; ++rep) {
#pragma unroll
            for (int l = 0; l < 2; ++l) {
#pragma unroll
                for (int w = 0; w < NQ; ++w) {
                    const float2 U00 = rotm[l * 6 + w][0];
                    const float2 U01 = rotm[l * 6 + w][1];
                    const float2 U10 = rotm[l * 6 + w][2];
                    const float2 U11 = rotm[l * 6 + w][3];
                    const int p = 5 - w;
                    const int bbit = (lane >> p) & 1;
                    const float px = __shfl_xor(amp.x, 1 << p, 64);
                    const float py = __shfl_xor(amp.y, 1 << p, 64);
                    const float2 ua = bbit ? U11 : U00;
                    const float2 ub = bbit ? U10 : U01;
                    float2 na;
                    na.x = ua.x * amp.x - ua.y * amp.y + ub.x * px - ub.y * py;
                    na.y = ua.x * amp.y + ua.y * amp.x + ub.x * py + ub.y * px;
                    amp = na;
                }
                const int r = (l == 0) ? 1 : 2;   // l % (NQ-1) + 1
#pragma unroll
                for (int w = 0; w < NQ; ++w) {
                    const int pc = 5 - w;
                    const int pt = 5 - ((w + r) % NQ);
                    const int src = lane ^ (((lane >> pc) & 1) << pt);
                    const float nx = __shfl(amp.x, src, 64);
                    const float ny = __shfl(amp.y, src, 64);
                    amp = make_float2(nx, ny);
                }
            }
        }
        sUt[col * DIM + lane] = amp;
    }
    __syncthreads();

    // phase 2: pack fragments (thread -> hi frag f = tid>>6 and lo frag f+16)
    {
        const int f  = tid >> 6;            // 0..15
        const int l  = lane;
        const int mt = f >> 1;
        const int t  = f & 1;
        const int m  = mt * 16 + (l & 15);
        short8 vhi, vlo;
#pragma unroll
        for (int j = 0; j < 8; ++j) {
            const int k = t * 32 + (l >> 4) * 8 + j;
            const float2 u = sUt[k * DIM + (m & 63)];
            const float val = (m < 64) ? u.x : u.y;
            const unsigned h = bf16_rne_u(val);
            vhi[j] = (short)h;
            const float fh = __builtin_bit_cast(float, h << 16);
            vlo[j] = (short)bf16_rne_u(val - fh);
        }
        ((int4*)wfrag)[f * 64 + l]        = __builtin_bit_cast(int4, vhi);
        ((int4*)wfrag)[(16 + f) * 64 + l] = __builtin_bit_cast(int4, vlo);
    }
}

// ---------------------------------------------------------------------------
// Main: 1 wave per (b,oy) row; 4 chunks of 16 samples (ox = ch*16 + n),
// depth-1 register software-pipeline on the feature loads.
//  B-fragments of F built directly from global: lane (qq,n) takes
//  F[k=qq*8+j][n] from x[b, c0(+2), 2oy+kh0(+1), 2ox .. 2ox+3].
//  G = (Whi+Wlo)·F (32 MFMA), P = Gre^2+Gim^2 -> LDS -> Z = S·P (2 MFMA),
//  z_q = Z[q][n] / Z[6][n]  (row 6 of S = ones -> ||f||^2, U unitary).
// ---------------------------------------------------------------------------
__global__ __launch_bounds__(256, 2) void qconv_mfma(const float* __restrict__ x,
                                                     const short* __restrict__ wfrag,
                                                     float* __restrict__ out) {
    __shared__ __align__(16) short sP[4][16 * PSTR];   // 10 KiB

    const int tid  = threadIdx.x;
    const int lane = tid & 63;
    const int wv   = tid >> 6;
    const int n    = lane & 15;
    const int qq   = lane >> 4;

    const int row = blockIdx.x * 4 + wv;   // 0..8063
    const int b   = row / OH;
    const int oy  = row - b * OH;

    // ---- x row pointers for this lane's 4 (c,kh) rows ----
    const int c0  = qq >> 1;
    const int kh0 = (qq & 1) * 2;
    const float* xb  = x + (size_t)b * CIN * HH * HH;
    const float* r00 = xb + ((c0    ) * HH + 2 * oy + kh0    ) * HH;
    const float* r01 = xb + ((c0    ) * HH + 2 * oy + kh0 + 1) * HH;
    const float* r10 = xb + ((c0 + 2) * HH + 2 * oy + kh0    ) * HH;
    const float* r11 = xb + ((c0 + 2) * HH + 2 * oy + kh0 + 1) * HH;

#define LOAD8(dst, ch_)                                                      \
    {                                                                        \
        const int oxl_ = min((ch_) * 16 + n, OH - 1);                        \
        const int fo_  = 2 * oxl_;                                           \
        dst[0] = *(const float2*)(r00 + fo_);                                \
        dst[1] = *(const float2*)(r00 + fo_ + 2);                            \
        dst[2] = *(const float2*)(r01 + fo_);                                \
        dst[3] = *(const float2*)(r01 + fo_ + 2);                            \
        dst[4] = *(const float2*)(r10 + fo_);                                \
        dst[5] = *(const float2*)(r10 + fo_ + 2);                            \
        dst[6] = *(const float2*)(r11 + fo_);                                \
        dst[7] = *(const float2*)(r11 + fo_ + 2);                            \
    }

    // prologue: loads for chunk 0 (in flight during W-frag preload below)
    float2 cur[8];
    LOAD8(cur, 0)

    // ---- W fragments (32 coalesced int4 loads, L2-resident) ----
    short8 whi[8][2], wlo[8][2];
    {
        const int4* wp = (const int4*)wfrag;
#pragma unroll
        for (int mt = 0; mt < 8; ++mt)
#pragma unroll
            for (int t = 0; t < 2; ++t) {
                const int f = mt * 2 + t;
                whi[mt][t] = __builtin_bit_cast(short8, wp[f * 64 + lane]);
                wlo[mt][t] = __builtin_bit_cast(short8, wp[(16 + f) * 64 + lane]);
            }
    }

    // ---- S fragments (rows 0..5 = Pauli-Z signs, row 6 = ones, rest 0) ----
    short8 sfr[2];
#pragma unroll
    for (int t = 0; t < 2; ++t) {
        short8 v;
#pragma unroll
        for (int j = 0; j < 8; ++j) {
            const int i = t * 32 + qq * 8 + j;
            unsigned short s;
            if (n < 6)       s = ((i >> (5 - n)) & 1) ? 0xBF80 : 0x3F80;
            else if (n == 6) s = 0x3F80;
            else             s = 0;
            v[j] = (short)s;
        }
        sfr[t] = v;
    }

    short* myP = sP[wv];

#pragma unroll
    for (int ch = 0; ch < 4; ++ch) {
        // ---- prefetch next chunk BEFORE consuming current (latency hiding)
        float2 nxt[8];
        if (ch < 3) LOAD8(nxt, ch + 1)

        // ---- pack current features into B fragments ----
        uint4 u0, u1;
        u0.x = pk_bf16(cur[0].x, cur[0].y);  u0.y = pk_bf16(cur[1].x, cur[1].y);
        u0.z = pk_bf16(cur[2].x, cur[2].y);  u0.w = pk_bf16(cur[3].x, cur[3].y);
        u1.x = pk_bf16(cur[4].x, cur[4].y);  u1.y = pk_bf16(cur[5].x, cur[5].y);
        u1.z = pk_bf16(cur[6].x, cur[6].y);  u1.w = pk_bf16(cur[7].x, cur[7].y);
        const short8 bf0 = __builtin_bit_cast(short8, u0);
        const short8 bf1 = __builtin_bit_cast(short8, u1);

        // ---- G = (Whi + Wlo) · F ----
        f32x4 acc[8];
#pragma unroll
        for (int mt = 0; mt < 8; ++mt) acc[mt] = (f32x4){0.f, 0.f, 0.f, 0.f};
#pragma unroll
        for (int mt = 0; mt < 8; ++mt) {
            acc[mt] = __builtin_amdgcn_mfma_f32_16x16x32_bf16(whi[mt][0], bf0, acc[mt], 0, 0, 0);
            acc[mt] = __builtin_amdgcn_mfma_f32_16x16x32_bf16(whi[mt][1], bf1, acc[mt], 0, 0, 0);
            acc[mt] = __builtin_amdgcn_mfma_f32_16x16x32_bf16(wlo[mt][0], bf0, acc[mt], 0, 0, 0);
            acc[mt] = __builtin_amdgcn_mfma_f32_16x16x32_bf16(wlo[mt][1], bf1, acc[mt], 0, 0, 0);
        }

        // ---- P = Gre^2 + Gim^2 -> bf16 (RNE) -> LDS (wave-private) ----
#pragma unroll
        for (int mt = 0; mt < 4; ++mt) {
            const float p0 = acc[mt][0] * acc[mt][0] + acc[mt + 4][0] * acc[mt + 4][0];
            const float p1 = acc[mt][1] * acc[mt][1] + acc[mt + 4][1] * acc[mt + 4][1];
            const float p2 = acc[mt][2] * acc[mt][2] + acc[mt + 4][2] * acc[mt + 4][2];
            const float p3 = acc[mt][3] * acc[mt][3] + acc[mt + 4][3] * acc[mt + 4][3];
            const unsigned w0 = pk_bf16(p0, p1);
            const unsigned w1 = pk_bf16(p2, p3);
            *((uint2*)(((unsigned*)myP) + n * (PSTR / 2) + mt * 8 + qq * 2)) =
                make_uint2(w0, w1);
        }

        // ---- Z = S · P ----
        const short8 p0f = *(const short8*)(myP + n * PSTR + qq * 8);
        const short8 p1f = *(const short8*)(myP + n * PSTR + 32 + qq * 8);
        f32x4 c2 = (f32x4){0.f, 0.f, 0.f, 0.f};
        c2 = __builtin_amdgcn_mfma_f32_16x16x32_bf16(sfr[0], p0f, c2, 0, 0, 0);
        c2 = __builtin_amdgcn_mfma_f32_16x16x32_bf16(sfr[1], p1f, c2, 0, 0, 0);

        // ---- normalize + store: Z row q = qq*4 + reg; norm = row 6 ----
        const float norm = __shfl(c2[2], 16 + n, 64);
        const float inv  = 1.0f / norm;
        const int ox = ch * 16 + n;
        if (ox < OH) {
            float* ob = out + ((size_t)b * NQ * OH + oy) * OH + ox;
            if (qq == 0) {
#pragma unroll
                for (int r = 0; r < 4; ++r)
                    __builtin_nontemporal_store(c2[r] * inv, ob + (size_t)r * (OH * OH));
            } else if (qq == 1) {
                __builtin_nontemporal_store(c2[0] * inv, ob + (size_t)4 * (OH * OH));
                __builtin_nontemporal_store(c2[1] * inv, ob + (size_t)5 * (OH * OH));
            }
        }

        // ---- rotate pipeline ----
        if (ch < 3) {
#pragma unroll
            for (int i = 0; i < 8; ++i) cur[i] = nxt[i];
        }
    }
#undef LOAD8
}

extern "C" void kernel_launch(void* const* d_in, const int* in_sizes, int n_in,
                              void* d_out, int out_size, void* d_ws, size_t ws_size,
                              hipStream_t stream) {
    const float* x   = (const float*)d_in[0];   // (128, 4, 128, 128) f32
    const float* wts = (const float*)d_in[1];   // (2, 6, 3) f32
    float* out = (float*)d_out;                 // (128, 6, 63, 63) f32
    short* wfrag = (short*)d_ws;                // 32 KiB

    prep<<<1, 1024, 0, stream>>>(wts, wfrag);
    qconv_mfma<<<(NB * OH) / 4, 256, 0, stream>>>(x, wfrag, out);
}

// Round 5
// 114.222 us; speedup vs baseline: 1.2047x; 1.1566x over previous
//
#include <hip/hip_runtime.h>

#define NQ   6
#define DIM  64
#define OH   63
#define HH   128
#define CIN  4
#define NB   128
#define PSTR 80   // P row stride in shorts (160B = 16B-aligned)

typedef __attribute__((ext_vector_type(8))) short short8;
typedef __attribute__((ext_vector_type(4))) float f32x4;

__device__ __forceinline__ unsigned bf16_rne_u(float f) {
    unsigned u = __builtin_bit_cast(unsigned, f);
    return (u + 0x7fffu + ((u >> 16) & 1u)) >> 16;   // round-nearest-even
}

#if __has_builtin(__builtin_amdgcn_cvt_pk_bf16_f32)
__device__ __forceinline__ unsigned pk_bf16(float a, float b) {
    typedef __attribute__((ext_vector_type(2))) __bf16 bf16x2_t;
    bf16x2_t v = __builtin_amdgcn_cvt_pk_bf16_f32(a, b);
    return __builtin_bit_cast(unsigned, v);
}
#else
__device__ __forceinline__ unsigned pk_bf16(float a, float b) {
    return bf16_rne_u(a) | (bf16_rne_u(b) << 16);
}
#endif

// ---------------------------------------------------------------------------
// Kernel A (multi-block, R2-proven): build the 64x64 circuit unitary,
// Ut[j*64+i] = U[i][j] (re,im). One block per basis column; 64 lanes = amps.
// ---------------------------------------------------------------------------
__global__ __launch_bounds__(64) void build_u(const float* __restrict__ wts,
                                              float2* __restrict__ Ut) {
    const int i   = threadIdx.x;
    const int col = blockIdx.x;
    float2 amp = make_float2(i == col ? 1.0f : 0.0f, 0.0f);
    const int ranges[2] = {1, 2};

    for (int rep = 0; rep < 2; ++rep) {
        for (int l = 0; l < 2; ++l) {
            for (int w = 0; w < NQ; ++w) {
                const float phi = wts[(l * NQ + w) * 3 + 0];
                const float th  = wts[(l * NQ + w) * 3 + 1];
                const float om  = wts[(l * NQ + w) * 3 + 2];
                const float hc = cosf(0.5f * th);
                const float hs = sinf(0.5f * th);
                const float ap = -0.5f * (phi + om);
                const float am = -0.5f * (phi - om);
                const float2 ep = make_float2(cosf(ap), sinf(ap));
                const float2 em = make_float2(cosf(am), sinf(am));
                const float2 U00 = make_float2( ep.x * hc,  ep.y * hc);
                const float2 U01 = make_float2(-em.x * hs,  em.y * hs);
                const float2 U10 = make_float2( em.x * hs,  em.y * hs);
                const float2 U11 = make_float2( ep.x * hc, -ep.y * hc);
                const int p = 5 - w;
                const int bbit = (i >> p) & 1;
                const float px = __shfl_xor(amp.x, 1 << p, 64);
                const float py = __shfl_xor(amp.y, 1 << p, 64);
                const float2 ua = bbit ? U11 : U00;
                const float2 ub = bbit ? U10 : U01;
                float2 na;
                na.x = ua.x * amp.x - ua.y * amp.y + ub.x * px - ub.y * py;
                na.y = ua.x * amp.y + ua.y * amp.x + ub.x * py + ub.y * px;
                amp = na;
            }
            const int r = ranges[l];
            for (int w = 0; w < NQ; ++w) {
                const int pc = 5 - w;
                const int pt = 5 - ((w + r) % NQ);
                const int src = i ^ (((i >> pc) & 1) << pt);
                const float nx = __shfl(amp.x, src, 64);
                const float ny = __shfl(amp.y, src, 64);
                amp = make_float2(nx, ny);
            }
        }
    }
    Ut[col * DIM + i] = amp;
}

// ---------------------------------------------------------------------------
// Kernel B (multi-block, R2-proven): pack W = [Re U; Im U] (128x64) into
// per-lane MFMA A-fragments, split hi/lo bf16.
//   frag f (0..15 hi, 16..31 lo): mt=(f&15)>>1, t=f&1;
//   lane l holds A[m = mt*16 + (l&15)][k = t*32 + (l>>4)*8 + j], j=0..7.
// ---------------------------------------------------------------------------
__global__ __launch_bounds__(64) void wprep(const float2* __restrict__ Ut,
                                            short* __restrict__ wfrag) {
    const int f = blockIdx.x;       // 0..31
    const int l = threadIdx.x;
    const int lo = f >> 4;
    const int mt = (f & 15) >> 1;
    const int t  = f & 1;
    const int m  = mt * 16 + (l & 15);
    short8 v;
#pragma unroll
    for (int j = 0; j < 8; ++j) {
        const int k = t * 32 + (l >> 4) * 8 + j;
        const float2 u = Ut[k * DIM + (m & 63)];
        const float val = (m < 64) ? u.x : u.y;
        const unsigned h = bf16_rne_u(val);
        if (lo == 0) {
            v[j] = (short)h;
        } else {
            const float fh = __builtin_bit_cast(float, h << 16);
            v[j] = (short)bf16_rne_u(val - fh);
        }
    }
    ((int4*)wfrag)[f * 64 + l] = __builtin_bit_cast(int4, v);
}

// ---------------------------------------------------------------------------
// Main (R4): 1 wave per (b,oy) row; 4 chunks of 16 samples (ox = ch*16 + n),
// depth-1 register software-pipeline on the feature loads.
//  B-fragments of F built directly from global: lane (qq,n) takes
//  F[k=qq*8+j][n] from x[b, c0(+2), 2oy+kh0(+1), 2ox .. 2ox+3].
//  G = (Whi+Wlo)·F (32 MFMA), P = Gre^2+Gim^2 -> LDS -> Z = S·P (2 MFMA),
//  z_q = Z[q][n] / Z[6][n]  (row 6 of S = ones -> ||f||^2, U unitary).
// ---------------------------------------------------------------------------
__global__ __launch_bounds__(256, 2) void qconv_mfma(const float* __restrict__ x,
                                                     const short* __restrict__ wfrag,
                                                     float* __restrict__ out) {
    __shared__ __align__(16) short sP[4][16 * PSTR];   // 10 KiB

    const int tid  = threadIdx.x;
    const int lane = tid & 63;
    const int wv   = tid >> 6;
    const int n    = lane & 15;
    const int qq   = lane >> 4;

    const int row = blockIdx.x * 4 + wv;   // 0..8063
    const int b   = row / OH;
    const int oy  = row - b * OH;

    // ---- x row pointers for this lane's 4 (c,kh) rows ----
    const int c0  = qq >> 1;
    const int kh0 = (qq & 1) * 2;
    const float* xb  = x + (size_t)b * CIN * HH * HH;
    const float* r00 = xb + ((c0    ) * HH + 2 * oy + kh0    ) * HH;
    const float* r01 = xb + ((c0    ) * HH + 2 * oy + kh0 + 1) * HH;
    const float* r10 = xb + ((c0 + 2) * HH + 2 * oy + kh0    ) * HH;
    const float* r11 = xb + ((c0 + 2) * HH + 2 * oy + kh0 + 1) * HH;

#define LOAD8(dst, ch_)                                                      \
    {                                                                        \
        const int oxl_ = min((ch_) * 16 + n, OH - 1);                        \
        const int fo_  = 2 * oxl_;                                           \
        dst[0] = *(const float2*)(r00 + fo_);                                \
        dst[1] = *(const float2*)(r00 + fo_ + 2);                            \
        dst[2] = *(const float2*)(r01 + fo_);                                \
        dst[3] = *(const float2*)(r01 + fo_ + 2);                            \
        dst[4] = *(const float2*)(r10 + fo_);                                \
        dst[5] = *(const float2*)(r10 + fo_ + 2);                            \
        dst[6] = *(const float2*)(r11 + fo_);                                \
        dst[7] = *(const float2*)(r11 + fo_ + 2);                            \
    }

    // prologue: loads for chunk 0 (in flight during W-frag preload below)
    float2 cur[8];
    LOAD8(cur, 0)

    // ---- W fragments (32 coalesced int4 loads, L2-resident) ----
    short8 whi[8][2], wlo[8][2];
    {
        const int4* wp = (const int4*)wfrag;
#pragma unroll
        for (int mt = 0; mt < 8; ++mt)
#pragma unroll
            for (int t = 0; t < 2; ++t) {
                const int f = mt * 2 + t;
                whi[mt][t] = __builtin_bit_cast(short8, wp[f * 64 + lane]);
                wlo[mt][t] = __builtin_bit_cast(short8, wp[(16 + f) * 64 + lane]);
            }
    }

    // ---- S fragments (rows 0..5 = Pauli-Z signs, row 6 = ones, rest 0) ----
    short8 sfr[2];
#pragma unroll
    for (int t = 0; t < 2; ++t) {
        short8 v;
#pragma unroll
        for (int j = 0; j < 8; ++j) {
            const int i = t * 32 + qq * 8 + j;
            unsigned short s;
            if (n < 6)       s = ((i >> (5 - n)) & 1) ? 0xBF80 : 0x3F80;
            else if (n == 6) s = 0x3F80;
            else             s = 0;
            v[j] = (short)s;
        }
        sfr[t] = v;
    }

    short* myP = sP[wv];

#pragma unroll
    for (int ch = 0; ch < 4; ++ch) {
        // ---- prefetch next chunk BEFORE consuming current (latency hiding)
        float2 nxt[8];
        if (ch < 3) LOAD8(nxt, ch + 1)

        // ---- pack current features into B fragments ----
        uint4 u0, u1;
        u0.x = pk_bf16(cur[0].x, cur[0].y);  u0.y = pk_bf16(cur[1].x, cur[1].y);
        u0.z = pk_bf16(cur[2].x, cur[2].y);  u0.w = pk_bf16(cur[3].x, cur[3].y);
        u1.x = pk_bf16(cur[4].x, cur[4].y);  u1.y = pk_bf16(cur[5].x, cur[5].y);
        u1.z = pk_bf16(cur[6].x, cur[6].y);  u1.w = pk_bf16(cur[7].x, cur[7].y);
        const short8 bf0 = __builtin_bit_cast(short8, u0);
        const short8 bf1 = __builtin_bit_cast(short8, u1);

        // ---- G = (Whi + Wlo) · F ----
        f32x4 acc[8];
#pragma unroll
        for (int mt = 0; mt < 8; ++mt) acc[mt] = (f32x4){0.f, 0.f, 0.f, 0.f};
#pragma unroll
        for (int mt = 0; mt < 8; ++mt) {
            acc[mt] = __builtin_amdgcn_mfma_f32_16x16x32_bf16(whi[mt][0], bf0, acc[mt], 0, 0, 0);
            acc[mt] = __builtin_amdgcn_mfma_f32_16x16x32_bf16(whi[mt][1], bf1, acc[mt], 0, 0, 0);
            acc[mt] = __builtin_amdgcn_mfma_f32_16x16x32_bf16(wlo[mt][0], bf0, acc[mt], 0, 0, 0);
            acc[mt] = __builtin_amdgcn_mfma_f32_16x16x32_bf16(wlo[mt][1], bf1, acc[mt], 0, 0, 0);
        }

        // ---- P = Gre^2 + Gim^2 -> bf16 (RNE) -> LDS (wave-private) ----
#pragma unroll
        for (int mt = 0; mt < 4; ++mt) {
            const float p0 = acc[mt][0] * acc[mt][0] + acc[mt + 4][0] * acc[mt + 4][0];
            const float p1 = acc[mt][1] * acc[mt][1] + acc[mt + 4][1] * acc[mt + 4][1];
            const float p2 = acc[mt][2] * acc[mt][2] + acc[mt + 4][2] * acc[mt + 4][2];
            const float p3 = acc[mt][3] * acc[mt][3] + acc[mt + 4][3] * acc[mt + 4][3];
            const unsigned w0 = pk_bf16(p0, p1);
            const unsigned w1 = pk_bf16(p2, p3);
            *((uint2*)(((unsigned*)myP) + n * (PSTR / 2) + mt * 8 + qq * 2)) =
                make_uint2(w0, w1);
        }

        // ---- Z = S · P ----
        const short8 p0f = *(const short8*)(myP + n * PSTR + qq * 8);
        const short8 p1f = *(const short8*)(myP + n * PSTR + 32 + qq * 8);
        f32x4 c2 = (f32x4){0.f, 0.f, 0.f, 0.f};
        c2 = __builtin_amdgcn_mfma_f32_16x16x32_bf16(sfr[0], p0f, c2, 0, 0, 0);
        c2 = __builtin_amdgcn_mfma_f32_16x16x32_bf16(sfr[1], p1f, c2, 0, 0, 0);

        // ---- normalize + store: Z row q = qq*4 + reg; norm = row 6 ----
        const float norm = __shfl(c2[2], 16 + n, 64);
        const float inv  = 1.0f / norm;
        const int ox = ch * 16 + n;
        if (ox < OH) {
            float* ob = out + ((size_t)b * NQ * OH + oy) * OH + ox;
            if (qq == 0) {
#pragma unroll
                for (int r = 0; r < 4; ++r)
                    __builtin_nontemporal_store(c2[r] * inv, ob + (size_t)r * (OH * OH));
            } else if (qq == 1) {
                __builtin_nontemporal_store(c2[0] * inv, ob + (size_t)4 * (OH * OH));
                __builtin_nontemporal_store(c2[1] * inv, ob + (size_t)5 * (OH * OH));
            }
        }

        // ---- rotate pipeline ----
        if (ch < 3) {
#pragma unroll
            for (int i = 0; i < 8; ++i) cur[i] = nxt[i];
        }
    }
#undef LOAD8
}

extern "C" void kernel_launch(void* const* d_in, const int* in_sizes, int n_in,
                              void* d_out, int out_size, void* d_ws, size_t ws_size,
                              hipStream_t stream) {
    const float* x   = (const float*)d_in[0];   // (128, 4, 128, 128) f32
    const float* wts = (const float*)d_in[1];   // (2, 6, 3) f32
    float* out = (float*)d_out;                 // (128, 6, 63, 63) f32

    float2* Ut    = (float2*)d_ws;                          // 32 KiB
    short*  wfrag = (short*)((char*)d_ws + 64 * 1024);      // 32 KiB

    build_u<<<64, 64, 0, stream>>>(wts, Ut);
    wprep<<<32, 64, 0, stream>>>(Ut, wfrag);
    qconv_mfma<<<(NB * OH) / 4, 256, 0, stream>>>(x, wfrag, out);
}

// Round 6
// 105.649 us; speedup vs baseline: 1.3025x; 1.0811x over previous
//
#include <hip/hip_runtime.h>

#define NQ   6
#define DIM  64
#define OH   63
#define HH   128
#define CIN  4
#define NB   128
#define PSTR 80   // P row stride in shorts (160B = 16B-aligned)

typedef __attribute__((ext_vector_type(8))) short short8;
typedef __attribute__((ext_vector_type(4))) float f32x4;

__device__ __forceinline__ unsigned bf16_rne_u(float f) {
    unsigned u = __builtin_bit_cast(unsigned, f);
    return (u + 0x7fffu + ((u >> 16) & 1u)) >> 16;   // round-nearest-even
}

#if __has_builtin(__builtin_amdgcn_cvt_pk_bf16_f32)
__device__ __forceinline__ unsigned pk_bf16(float a, float b) {
    typedef __attribute__((ext_vector_type(2))) __bf16 bf16x2_t;
    bf16x2_t v = __builtin_amdgcn_cvt_pk_bf16_f32(a, b);
    return __builtin_bit_cast(unsigned, v);
}
#else
__device__ __forceinline__ unsigned pk_bf16(float a, float b) {
    return bf16_rne_u(a) | (bf16_rne_u(b) << 16);
}
#endif

// ---------------------------------------------------------------------------
// Kernel A: build the 64x64 circuit unitary, Ut[j*64+i] = U[i][j] (re,im).
// One block per basis column; 64 lanes = 64 amplitudes.
// ---------------------------------------------------------------------------
__global__ __launch_bounds__(64) void build_u(const float* __restrict__ wts,
                                              float2* __restrict__ Ut) {
    const int i   = threadIdx.x;
    const int col = blockIdx.x;
    float2 amp = make_float2(i == col ? 1.0f : 0.0f, 0.0f);
    const int ranges[2] = {1, 2};

    for (int rep = 0; rep < 2; ++rep) {
        for (int l = 0; l < 2; ++l) {
            for (int w = 0; w < NQ; ++w) {
                const float phi = wts[(l * NQ + w) * 3 + 0];
                const float th  = wts[(l * NQ + w) * 3 + 1];
                const float om  = wts[(l * NQ + w) * 3 + 2];
                const float hc = cosf(0.5f * th);
                const float hs = sinf(0.5f * th);
                const float ap = -0.5f * (phi + om);
                const float am = -0.5f * (phi - om);
                const float2 ep = make_float2(cosf(ap), sinf(ap));
                const float2 em = make_float2(cosf(am), sinf(am));
                const float2 U00 = make_float2( ep.x * hc,  ep.y * hc);
                const float2 U01 = make_float2(-em.x * hs,  em.y * hs);
                const float2 U10 = make_float2( em.x * hs,  em.y * hs);
                const float2 U11 = make_float2( ep.x * hc, -ep.y * hc);
                const int p = 5 - w;
                const int bbit = (i >> p) & 1;
                const float px = __shfl_xor(amp.x, 1 << p, 64);
                const float py = __shfl_xor(amp.y, 1 << p, 64);
                const float2 ua = bbit ? U11 : U00;
                const float2 ub = bbit ? U10 : U01;
                float2 na;
                na.x = ua.x * amp.x - ua.y * amp.y + ub.x * px - ub.y * py;
                na.y = ua.x * amp.y + ua.y * amp.x + ub.x * py + ub.y * px;
                amp = na;
            }
            const int r = ranges[l];
            for (int w = 0; w < NQ; ++w) {
                const int pc = 5 - w;
                const int pt = 5 - ((w + r) % NQ);
                const int src = i ^ (((i >> pc) & 1) << pt);
                const float nx = __shfl(amp.x, src, 64);
                const float ny = __shfl(amp.y, src, 64);
                amp = make_float2(nx, ny);
            }
        }
    }
    Ut[col * DIM + i] = amp;
}

// ---------------------------------------------------------------------------
// Kernel B: pack W = [Re U; Im U] (128x64) into per-lane MFMA A-fragments
// (single bf16, RNE).  frag f (0..15): mt=f>>1, t=f&1;
// lane l holds A[m = mt*16 + (l&15)][k = t*32 + (l>>4)*8 + j], j=0..7.
// ---------------------------------------------------------------------------
__global__ __launch_bounds__(64) void wprep(const float2* __restrict__ Ut,
                                            short* __restrict__ wfrag) {
    const int f = blockIdx.x;       // 0..15
    const int l = threadIdx.x;
    const int mt = f >> 1;
    const int t  = f & 1;
    const int m  = mt * 16 + (l & 15);
    short8 v;
#pragma unroll
    for (int j = 0; j < 8; ++j) {
        const int k = t * 32 + (l >> 4) * 8 + j;
        const float2 u = Ut[k * DIM + (m & 63)];
        const float val = (m < 64) ? u.x : u.y;
        v[j] = (short)bf16_rne_u(val);
    }
    ((int4*)wfrag)[f * 64 + l] = __builtin_bit_cast(int4, v);
}

// ---------------------------------------------------------------------------
// Main: 1 wave per (b,oy) row; 4 chunks of 16 samples (ox = ch*16 + n),
// depth-1 register software-pipeline on the feature loads.
//  B-fragments of F built directly from global: lane (qq,n) takes
//  F[k=qq*8+j][n] from x[b, c0(+2), 2oy+kh0(+1), 2ox .. 2ox+3].
//  G = W·F (16 MFMA, single bf16 W), P = Gre^2+Gim^2 -> LDS ->
//  Z = S·P (2 MFMA), z_q = Z[q][n] / Z[6][n]  (row 6 of S = ones).
// ---------------------------------------------------------------------------
__global__ __launch_bounds__(256, 3) void qconv_mfma(const float* __restrict__ x,
                                                     const short* __restrict__ wfrag,
                                                     float* __restrict__ out) {
    __shared__ __align__(16) short sP[4][16 * PSTR];   // 10 KiB

    const int tid  = threadIdx.x;
    const int lane = tid & 63;
    const int wv   = tid >> 6;
    const int n    = lane & 15;
    const int qq   = lane >> 4;

    const int row = blockIdx.x * 4 + wv;   // 0..8063
    const int b   = row / OH;
    const int oy  = row - b * OH;

    // ---- x row pointers for this lane's 4 (c,kh) rows ----
    const int c0  = qq >> 1;
    const int kh0 = (qq & 1) * 2;
    const float* xb  = x + (size_t)b * CIN * HH * HH;
    const float* r00 = xb + ((c0    ) * HH + 2 * oy + kh0    ) * HH;
    const float* r01 = xb + ((c0    ) * HH + 2 * oy + kh0 + 1) * HH;
    const float* r10 = xb + ((c0 + 2) * HH + 2 * oy + kh0    ) * HH;
    const float* r11 = xb + ((c0 + 2) * HH + 2 * oy + kh0 + 1) * HH;

#define LOAD8(dst, ch_)                                                      \
    {                                                                        \
        const int oxl_ = min((ch_) * 16 + n, OH - 1);                        \
        const int fo_  = 2 * oxl_;                                           \
        dst[0] = *(const float2*)(r00 + fo_);                                \
        dst[1] = *(const float2*)(r00 + fo_ + 2);                            \
        dst[2] = *(const float2*)(r01 + fo_);                                \
        dst[3] = *(const float2*)(r01 + fo_ + 2);                            \
        dst[4] = *(const float2*)(r10 + fo_);                                \
        dst[5] = *(const float2*)(r10 + fo_ + 2);                            \
        dst[6] = *(const float2*)(r11 + fo_);                                \
        dst[7] = *(const float2*)(r11 + fo_ + 2);                            \
    }

    // prologue: loads for chunk 0 (in flight during W-frag preload below)
    float2 cur[8];
    LOAD8(cur, 0)

    // ---- W fragments (16 coalesced int4 loads, L2-resident) ----
    short8 wfr[8][2];
    {
        const int4* wp = (const int4*)wfrag;
#pragma unroll
        for (int mt = 0; mt < 8; ++mt)
#pragma unroll
            for (int t = 0; t < 2; ++t)
                wfr[mt][t] = __builtin_bit_cast(short8, wp[(mt * 2 + t) * 64 + lane]);
    }

    // ---- S fragments (rows 0..5 = Pauli-Z signs, row 6 = ones, rest 0) ----
    short8 sfr[2];
#pragma unroll
    for (int t = 0; t < 2; ++t) {
        short8 v;
#pragma unroll
        for (int j = 0; j < 8; ++j) {
            const int i = t * 32 + qq * 8 + j;
            unsigned short s;
            if (n < 6)       s = ((i >> (5 - n)) & 1) ? 0xBF80 : 0x3F80;
            else if (n == 6) s = 0x3F80;
            else             s = 0;
            v[j] = (short)s;
        }
        sfr[t] = v;
    }

    short* myP = sP[wv];

#pragma unroll
    for (int ch = 0; ch < 4; ++ch) {
        // ---- prefetch next chunk BEFORE consuming current (latency hiding)
        float2 nxt[8];
        if (ch < 3) LOAD8(nxt, ch + 1)

        // ---- pack current features into B fragments ----
        uint4 u0, u1;
        u0.x = pk_bf16(cur[0].x, cur[0].y);  u0.y = pk_bf16(cur[1].x, cur[1].y);
        u0.z = pk_bf16(cur[2].x, cur[2].y);  u0.w = pk_bf16(cur[3].x, cur[3].y);
        u1.x = pk_bf16(cur[4].x, cur[4].y);  u1.y = pk_bf16(cur[5].x, cur[5].y);
        u1.z = pk_bf16(cur[6].x, cur[6].y);  u1.w = pk_bf16(cur[7].x, cur[7].y);
        const short8 bf0 = __builtin_bit_cast(short8, u0);
        const short8 bf1 = __builtin_bit_cast(short8, u1);

        // ---- G = W · F (16 MFMA) ----
        f32x4 acc[8];
#pragma unroll
        for (int mt = 0; mt < 8; ++mt) acc[mt] = (f32x4){0.f, 0.f, 0.f, 0.f};
#pragma unroll
        for (int mt = 0; mt < 8; ++mt) {
            acc[mt] = __builtin_amdgcn_mfma_f32_16x16x32_bf16(wfr[mt][0], bf0, acc[mt], 0, 0, 0);
            acc[mt] = __builtin_amdgcn_mfma_f32_16x16x32_bf16(wfr[mt][1], bf1, acc[mt], 0, 0, 0);
        }

        // ---- P = Gre^2 + Gim^2 -> bf16 (RNE) -> LDS (wave-private) ----
#pragma unroll
        for (int mt = 0; mt < 4; ++mt) {
            const float p0 = acc[mt][0] * acc[mt][0] + acc[mt + 4][0] * acc[mt + 4][0];
            const float p1 = acc[mt][1] * acc[mt][1] + acc[mt + 4][1] * acc[mt + 4][1];
            const float p2 = acc[mt][2] * acc[mt][2] + acc[mt + 4][2] * acc[mt + 4][2];
            const float p3 = acc[mt][3] * acc[mt][3] + acc[mt + 4][3] * acc[mt + 4][3];
            const unsigned w0 = pk_bf16(p0, p1);
            const unsigned w1 = pk_bf16(p2, p3);
            *((uint2*)(((unsigned*)myP) + n * (PSTR / 2) + mt * 8 + qq * 2)) =
                make_uint2(w0, w1);
        }

        // ---- Z = S · P ----
        const short8 p0f = *(const short8*)(myP + n * PSTR + qq * 8);
        const short8 p1f = *(const short8*)(myP + n * PSTR + 32 + qq * 8);
        f32x4 c2 = (f32x4){0.f, 0.f, 0.f, 0.f};
        c2 = __builtin_amdgcn_mfma_f32_16x16x32_bf16(sfr[0], p0f, c2, 0, 0, 0);
        c2 = __builtin_amdgcn_mfma_f32_16x16x32_bf16(sfr[1], p1f, c2, 0, 0, 0);

        // ---- normalize + store: Z row q = qq*4 + reg; norm = row 6 ----
        const float norm = __shfl(c2[2], 16 + n, 64);
        const float inv  = 1.0f / norm;
        const int ox = ch * 16 + n;
        if (ox < OH) {
            float* ob = out + ((size_t)b * NQ * OH + oy) * OH + ox;
            if (qq == 0) {
#pragma unroll
                for (int r = 0; r < 4; ++r)
                    __builtin_nontemporal_store(c2[r] * inv, ob + (size_t)r * (OH * OH));
            } else if (qq == 1) {
                __builtin_nontemporal_store(c2[0] * inv, ob + (size_t)4 * (OH * OH));
                __builtin_nontemporal_store(c2[1] * inv, ob + (size_t)5 * (OH * OH));
            }
        }

        // ---- rotate pipeline ----
        if (ch < 3) {
#pragma unroll
            for (int i = 0; i < 8; ++i) cur[i] = nxt[i];
        }
    }
#undef LOAD8
}

extern "C" void kernel_launch(void* const* d_in, const int* in_sizes, int n_in,
                              void* d_out, int out_size, void* d_ws, size_t ws_size,
                              hipStream_t stream) {
    const float* x   = (const float*)d_in[0];   // (128, 4, 128, 128) f32
    const float* wts = (const float*)d_in[1];   // (2, 6, 3) f32
    float* out = (float*)d_out;                 // (128, 6, 63, 63) f32

    float2* Ut    = (float2*)d_ws;                          // 32 KiB
    short*  wfrag = (short*)((char*)d_ws + 64 * 1024);      // 16 KiB

    build_u<<<64, 64, 0, stream>>>(wts, Ut);
    wprep<<<16, 64, 0, stream>>>(Ut, wfrag);
    qconv_mfma<<<(NB * OH) / 4, 256, 0, stream>>>(x, wfrag, out);
}

// Round 7
// 93.442 us; speedup vs baseline: 1.4726x; 1.1306x over previous
//
#include <hip/hip_runtime.h>

#define NQ   6
#define DIM  64
#define OH   63
#define HH   128
#define CIN  4
#define NB   128
#define PSTR 80   // P row stride in shorts (160B = 16B-aligned)

typedef __attribute__((ext_vector_type(8))) short short8;
typedef __attribute__((ext_vector_type(4))) float f32x4;

__device__ __forceinline__ unsigned bf16_rne_u(float f) {
    unsigned u = __builtin_bit_cast(unsigned, f);
    return (u + 0x7fffu + ((u >> 16) & 1u)) >> 16;   // round-nearest-even
}

#if __has_builtin(__builtin_amdgcn_cvt_pk_bf16_f32)
__device__ __forceinline__ unsigned pk_bf16(float a, float b) {
    typedef __attribute__((ext_vector_type(2))) __bf16 bf16x2_t;
    bf16x2_t v = __builtin_amdgcn_cvt_pk_bf16_f32(a, b);
    return __builtin_bit_cast(unsigned, v);
}
#else
__device__ __forceinline__ unsigned pk_bf16(float a, float b) {
    return bf16_rne_u(a) | (bf16_rne_u(b) << 16);
}
#endif

// ---------------------------------------------------------------------------
// Fused build: one block per basis column col; 64 lanes = 64 amplitudes.
// Lanes 0..11 each own one gate's rotation matrix (one transcendental pass);
// gate matrices broadcast via shfl during the 24 applications. After the
// circuit, lane i holds U[i][col] and scatters its two bf16 contributions
// (Re -> frag row i, Im -> frag row 64+i) straight into the wfrag layout:
//   frag f (0..15): mt=f>>1, t=f&1; lane l holds
//   A[m = mt*16 + (l&15)][k = t*32 + (l>>4)*8 + j], j=0..7.
// Frags 16..17 hold the S-matrix B..A-fragments (lane-only data; every block
// writes identical values - benign race).
// ---------------------------------------------------------------------------
__global__ __launch_bounds__(64) void build_wfrag(const float* __restrict__ wts,
                                                  short* __restrict__ wfrag) {
    const int i   = threadIdx.x;
    const int col = blockIdx.x;

    // per-lane gate matrix (lanes 0..11 hold the 12 unique gates)
    const int g = (i < 12) ? i : 0;
    const float phi = wts[g * 3 + 0];
    const float th  = wts[g * 3 + 1];
    const float om  = wts[g * 3 + 2];
    const float hc = cosf(0.5f * th);
    const float hs = sinf(0.5f * th);
    const float ap = -0.5f * (phi + om);
    const float am = -0.5f * (phi - om);
    // U00=(a,b) U01=(-c,d) U10=(c,d) U11=(a,-b)
    const float ga = cosf(ap) * hc;
    const float gb = sinf(ap) * hc;
    const float gc = cosf(am) * hs;
    const float gd = sinf(am) * hs;

    float2 amp = make_float2(i == col ? 1.0f : 0.0f, 0.0f);

    for (int rep = 0; rep < 2; ++rep) {
        for (int l = 0; l < 2; ++l) {
            for (int w = 0; w < NQ; ++w) {
                const int src = l * 6 + w;
                const float a = __shfl(ga, src, 64);
                const float b = __shfl(gb, src, 64);
                const float c = __shfl(gc, src, 64);
                const float d = __shfl(gd, src, 64);
                const int p = 5 - w;
                const int bbit = (i >> p) & 1;
                const float px = __shfl_xor(amp.x, 1 << p, 64);
                const float py = __shfl_xor(amp.y, 1 << p, 64);
                const float uax = a;
                const float uay = bbit ? -b : b;
                const float ubx = bbit ? c : -c;
                const float uby = d;
                float2 na;
                na.x = uax * amp.x - uay * amp.y + ubx * px - uby * py;
                na.y = uax * amp.y + uay * amp.x + ubx * py + uby * px;
                amp = na;
            }
            const int r = (l == 0) ? 1 : 2;   // l % (NQ-1) + 1
            for (int w = 0; w < NQ; ++w) {
                const int pc = 5 - w;
                const int pt = 5 - ((w + r) % NQ);
                const int src = i ^ (((i >> pc) & 1) << pt);
                const float nx = __shfl(amp.x, src, 64);
                const float ny = __shfl(amp.y, src, 64);
                amp = make_float2(nx, ny);
            }
        }
    }

    // ---- scatter this column's W contributions into wfrag ----
    const int t    = col >> 5;
    const int quad = (col >> 3) & 3;
    const int j    = col & 7;
    const int lre  = quad * 16 + (i & 15);
    const int fre  = ((i >> 4)    ) * 2 + t;   // Re: rows 0..63
    const int fim  = ((i >> 4) + 4) * 2 + t;   // Im: rows 64..127
    wfrag[(fre * 64 + lre) * 8 + j] = (short)bf16_rne_u(amp.x);
    wfrag[(fim * 64 + lre) * 8 + j] = (short)bf16_rne_u(amp.y);

    // ---- S fragments (frags 16..17): rows 0..5 Pauli-Z signs, 6 ones ----
    {
        const int n  = i & 15;
        const int qq = i >> 4;
#pragma unroll
        for (int tt = 0; tt < 2; ++tt) {
            short8 v;
#pragma unroll
            for (int jj = 0; jj < 8; ++jj) {
                const int k = tt * 32 + qq * 8 + jj;
                unsigned short s;
                if (n < 6)       s = ((k >> (5 - n)) & 1) ? 0xBF80 : 0x3F80;
                else if (n == 6) s = 0x3F80;
                else             s = 0;
                v[jj] = (short)s;
            }
            ((int4*)wfrag)[(16 + tt) * 64 + i] = __builtin_bit_cast(int4, v);
        }
    }
}

// ---------------------------------------------------------------------------
// Main: grid 4032; block -> (4 rows) x (half of ox range). Each wave owns one
// (b,oy) row-half = 2 chunks of 16 samples, depth-1 register pipeline.
//  B-fragments of F built directly from global: lane (qq,n) takes
//  F[k=qq*8+j][n] from x[b, c0(+2), 2oy+kh0(+1), 2ox .. 2ox+3].
//  G = W·F (16 MFMA), P = Gre^2+Gim^2 -> LDS -> Z = S·P (2 MFMA),
//  z_q = Z[q][n] / Z[6][n]  (row 6 of S = ones -> ||f||^2, U unitary).
// ---------------------------------------------------------------------------
__global__ __launch_bounds__(256, 3) void qconv_mfma(const float* __restrict__ x,
                                                     const short* __restrict__ wfrag,
                                                     float* __restrict__ out) {
    __shared__ __align__(16) short sP[4][16 * PSTR];   // 10 KiB

    const int tid  = threadIdx.x;
    const int lane = tid & 63;
    const int wv   = tid >> 6;
    const int n    = lane & 15;
    const int qq   = lane >> 4;

    const int bid   = blockIdx.x;
    const int row   = (bid >> 1) * 4 + wv;   // 0..8063
    const int half2 = (bid & 1) * 2;         // global chunk base (0 or 2)
    const int b     = row / OH;
    const int oy    = row - b * OH;

    // ---- x row pointers for this lane's 4 (c,kh) rows ----
    const int c0  = qq >> 1;
    const int kh0 = (qq & 1) * 2;
    const float* xb  = x + (size_t)b * CIN * HH * HH;
    const float* r00 = xb + ((c0    ) * HH + 2 * oy + kh0    ) * HH;
    const float* r01 = xb + ((c0    ) * HH + 2 * oy + kh0 + 1) * HH;
    const float* r10 = xb + ((c0 + 2) * HH + 2 * oy + kh0    ) * HH;
    const float* r11 = xb + ((c0 + 2) * HH + 2 * oy + kh0 + 1) * HH;

#define LOAD8(dst, chg_)                                                     \
    {                                                                        \
        const int oxl_ = min((chg_) * 16 + n, OH - 1);                       \
        const int fo_  = 2 * oxl_;                                           \
        dst[0] = *(const float2*)(r00 + fo_);                                \
        dst[1] = *(const float2*)(r00 + fo_ + 2);                            \
        dst[2] = *(const float2*)(r01 + fo_);                                \
        dst[3] = *(const float2*)(r01 + fo_ + 2);                            \
        dst[4] = *(const float2*)(r10 + fo_);                                \
        dst[5] = *(const float2*)(r10 + fo_ + 2);                            \
        dst[6] = *(const float2*)(r11 + fo_);                                \
        dst[7] = *(const float2*)(r11 + fo_ + 2);                            \
    }

    // prologue: loads for first chunk (in flight during W-frag preload)
    float2 cur[8];
    LOAD8(cur, half2)

    // ---- W fragments + S fragments (18 coalesced int4 loads, L2-resident)
    short8 wfr[8][2], sfr[2];
    {
        const int4* wp = (const int4*)wfrag;
#pragma unroll
        for (int mt = 0; mt < 8; ++mt)
#pragma unroll
            for (int t = 0; t < 2; ++t)
                wfr[mt][t] = __builtin_bit_cast(short8, wp[(mt * 2 + t) * 64 + lane]);
#pragma unroll
        for (int t = 0; t < 2; ++t)
            sfr[t] = __builtin_bit_cast(short8, wp[(16 + t) * 64 + lane]);
    }

    short* myP = sP[wv];

#pragma unroll
    for (int ch = 0; ch < 2; ++ch) {
        // ---- prefetch next chunk BEFORE consuming current (latency hiding)
        float2 nxt[8];
        if (ch < 1) LOAD8(nxt, half2 + 1)

        // ---- pack current features into B fragments ----
        uint4 u0, u1;
        u0.x = pk_bf16(cur[0].x, cur[0].y);  u0.y = pk_bf16(cur[1].x, cur[1].y);
        u0.z = pk_bf16(cur[2].x, cur[2].y);  u0.w = pk_bf16(cur[3].x, cur[3].y);
        u1.x = pk_bf16(cur[4].x, cur[4].y);  u1.y = pk_bf16(cur[5].x, cur[5].y);
        u1.z = pk_bf16(cur[6].x, cur[6].y);  u1.w = pk_bf16(cur[7].x, cur[7].y);
        const short8 bf0 = __builtin_bit_cast(short8, u0);
        const short8 bf1 = __builtin_bit_cast(short8, u1);

        // ---- G = W · F (16 MFMA) ----
        f32x4 acc[8];
#pragma unroll
        for (int mt = 0; mt < 8; ++mt) acc[mt] = (f32x4){0.f, 0.f, 0.f, 0.f};
#pragma unroll
        for (int mt = 0; mt < 8; ++mt) {
            acc[mt] = __builtin_amdgcn_mfma_f32_16x16x32_bf16(wfr[mt][0], bf0, acc[mt], 0, 0, 0);
            acc[mt] = __builtin_amdgcn_mfma_f32_16x16x32_bf16(wfr[mt][1], bf1, acc[mt], 0, 0, 0);
        }

        // ---- P = Gre^2 + Gim^2 -> bf16 (RNE) -> LDS (wave-private) ----
#pragma unroll
        for (int mt = 0; mt < 4; ++mt) {
            const float p0 = acc[mt][0] * acc[mt][0] + acc[mt + 4][0] * acc[mt + 4][0];
            const float p1 = acc[mt][1] * acc[mt][1] + acc[mt + 4][1] * acc[mt + 4][1];
            const float p2 = acc[mt][2] * acc[mt][2] + acc[mt + 4][2] * acc[mt + 4][2];
            const float p3 = acc[mt][3] * acc[mt][3] + acc[mt + 4][3] * acc[mt + 4][3];
            const unsigned w0 = pk_bf16(p0, p1);
            const unsigned w1 = pk_bf16(p2, p3);
            *((uint2*)(((unsigned*)myP) + n * (PSTR / 2) + mt * 8 + qq * 2)) =
                make_uint2(w0, w1);
        }

        // ---- Z = S · P ----
        const short8 p0f = *(const short8*)(myP + n * PSTR + qq * 8);
        const short8 p1f = *(const short8*)(myP + n * PSTR + 32 + qq * 8);
        f32x4 c2 = (f32x4){0.f, 0.f, 0.f, 0.f};
        c2 = __builtin_amdgcn_mfma_f32_16x16x32_bf16(sfr[0], p0f, c2, 0, 0, 0);
        c2 = __builtin_amdgcn_mfma_f32_16x16x32_bf16(sfr[1], p1f, c2, 0, 0, 0);

        // ---- normalize + store: Z row q = qq*4 + reg; norm = row 6 ----
        const float norm = __shfl(c2[2], 16 + n, 64);
        const float inv  = 1.0f / norm;
        const int ox = (half2 + ch) * 16 + n;
        if (ox < OH) {
            float* ob = out + ((size_t)b * NQ * OH + oy) * OH + ox;
            if (qq == 0) {
#pragma unroll
                for (int r = 0; r < 4; ++r)
                    __builtin_nontemporal_store(c2[r] * inv, ob + (size_t)r * (OH * OH));
            } else if (qq == 1) {
                __builtin_nontemporal_store(c2[0] * inv, ob + (size_t)4 * (OH * OH));
                __builtin_nontemporal_store(c2[1] * inv, ob + (size_t)5 * (OH * OH));
            }
        }

        // ---- rotate pipeline ----
        if (ch < 1) {
#pragma unroll
            for (int i = 0; i < 8; ++i) cur[i] = nxt[i];
        }
    }
#undef LOAD8
}

extern "C" void kernel_launch(void* const* d_in, const int* in_sizes, int n_in,
                              void* d_out, int out_size, void* d_ws, size_t ws_size,
                              hipStream_t stream) {
    const float* x   = (const float*)d_in[0];   // (128, 4, 128, 128) f32
    const float* wts = (const float*)d_in[1];   // (2, 6, 3) f32
    float* out = (float*)d_out;                 // (128, 6, 63, 63) f32
    short* wfrag = (short*)d_ws;                // 18 frags * 1 KiB

    build_wfrag<<<64, 64, 0, stream>>>(wts, wfrag);
    qconv_mfma<<<(NB * OH) / 2, 256, 0, stream>>>(x, wfrag, out);
}